// Round 1
// baseline (361.818 us; speedup 1.0000x reference)
//
#include <hip/hip_runtime.h>
#include <float.h>

#define C_DEPTH 128
#define H_DIM 128
#define W_DIM 128
#define NPIX (H_DIM * W_DIM)
#define N_SAMP 32
#define N_FINAL 8
#define N_LINES 50000

// ---------------------------------------------------------------------------
// Pre-pass: transpose features (C,H,W) -> (H*W, C) so that per-sample channel
// gathers are contiguous across lanes (lane = channel).
// Tile: 64 pixels x 128 channels via LDS (pad 129 to kill bank conflicts).
// ---------------------------------------------------------------------------
__global__ __launch_bounds__(256) void transpose_chw_hwc(
    const float* __restrict__ in, float* __restrict__ out) {
    __shared__ float tile[64 * 129];
    const int p0 = blockIdx.x * 64;
    const int t = threadIdx.x;

    // Load: lanes contiguous in pixel dim -> coalesced 256B per wave.
    const int p_local = t & 63;
    const int cg = t >> 6;  // 0..3, each covers 32 channels
    #pragma unroll
    for (int i = 0; i < 32; ++i) {
        const int ch = cg * 32 + i;
        tile[p_local * 129 + ch] = in[ch * NPIX + p0 + p_local];
    }
    __syncthreads();

    // Store: lanes contiguous in channel dim -> coalesced writes.
    const int ch = t & 127;
    const int pg = t >> 7;  // 0..1, each covers 32 pixels
    #pragma unroll
    for (int i = 0; i < 32; ++i) {
        const int p = pg * 32 + i;
        out[(p0 + p) * C_DEPTH + ch] = tile[p * 129 + ch];
    }
}

// ---------------------------------------------------------------------------
// Main kernel: 1 block = 1 line, 128 threads = 128 channels.
// Threads 0..31 compute per-sample corner offsets + bilinear weights into LDS.
// Each thread gathers 4 corners per sample (coalesced across lanes), bilinear
// combines, max-pools groups of 4 samples -> 8 finals, writes 2x float4.
// Output layout: out[line*1024 + c*8 + f]  (c major, f minor) per reference.
// ---------------------------------------------------------------------------
__global__ __launch_bounds__(128) void line_pool(
    const float* __restrict__ ft,       // (H*W, C) transposed features
    const float* __restrict__ lines,    // (N_LINES, 4)
    float* __restrict__ out) {
    __shared__ int4   s_off[N_SAMP];    // corner offsets pre-multiplied by C
    __shared__ float4 s_w[N_SAMP];      // bilinear weights (w00,w10,w01,w11)

    const int line = blockIdx.x;
    const int t = threadIdx.x;

    if (t < N_SAMP) {
        const float4 l = reinterpret_cast<const float4*>(lines)[line];
        // t in [0,31]; ts = t/31 gives exactly 1.0 at t=31 (matches linspace).
        const float ts = (float)t / 31.0f;
        const float px = l.x * ts + l.z * (1.0f - ts) - 0.5f;
        const float py = l.y * ts + l.w * (1.0f - ts) - 0.5f;
        // Reference: clamp AFTER floor, weights from the CLAMPED float coords.
        const float px0 = fminf(fmaxf(floorf(px), 0.0f), (float)(W_DIM - 1));
        const float py0 = fminf(fmaxf(floorf(py), 0.0f), (float)(H_DIM - 1));
        const float px1 = fminf(px0 + 1.0f, (float)(W_DIM - 1));
        const float py1 = fminf(py0 + 1.0f, (float)(H_DIM - 1));
        const int ix0 = (int)px0, iy0 = (int)py0;
        const int ix1 = (int)px1, iy1 = (int)py1;
        const float wx0 = px1 - px, wx1 = px - px0;
        const float wy0 = py1 - py, wy1 = py - py0;
        s_off[t] = make_int4((iy0 * W_DIM + ix0) * C_DEPTH,
                             (iy1 * W_DIM + ix0) * C_DEPTH,
                             (iy0 * W_DIM + ix1) * C_DEPTH,
                             (iy1 * W_DIM + ix1) * C_DEPTH);
        s_w[t] = make_float4(wy0 * wx0, wy1 * wx0, wy0 * wx1, wy1 * wx1);
    }
    __syncthreads();

    const int c = t;  // channel
    float acc[N_FINAL];
    #pragma unroll
    for (int f = 0; f < N_FINAL; ++f) acc[f] = -FLT_MAX;

    #pragma unroll
    for (int s = 0; s < N_SAMP; ++s) {
        const int4   o  = s_off[s];   // LDS broadcast (same addr all lanes)
        const float4 wv = s_w[s];
        const float v = ft[o.x + c] * wv.x + ft[o.y + c] * wv.y +
                        ft[o.z + c] * wv.z + ft[o.w + c] * wv.w;
        acc[s >> 2] = fmaxf(acc[s >> 2], v);
    }

    float* op = out + (size_t)line * (C_DEPTH * N_FINAL) + c * N_FINAL;
    reinterpret_cast<float4*>(op)[0] = make_float4(acc[0], acc[1], acc[2], acc[3]);
    reinterpret_cast<float4*>(op)[1] = make_float4(acc[4], acc[5], acc[6], acc[7]);
}

extern "C" void kernel_launch(void* const* d_in, const int* in_sizes, int n_in,
                              void* d_out, int out_size, void* d_ws, size_t ws_size,
                              hipStream_t stream) {
    const float* feat  = (const float*)d_in[0];   // (128,128,128) fp32
    const float* lines = (const float*)d_in[1];   // (50000,4) fp32
    float* out = (float*)d_out;                   // (50000, 1024) fp32
    float* ft  = (float*)d_ws;                    // 8 MB transposed features

    transpose_chw_hwc<<<NPIX / 64, 256, 0, stream>>>(feat, ft);
    line_pool<<<N_LINES, 128, 0, stream>>>(ft, lines, out);
}

// Round 3
// 276.294 us; speedup vs baseline: 1.3095x; 1.3095x over previous
//
#include <hip/hip_runtime.h>
#include <hip/hip_fp16.h>
#include <float.h>

#define C_DEPTH 128
#define H_DIM 128
#define W_DIM 128
#define NPIX (H_DIM * W_DIM)
#define N_SAMP 32
#define N_FINAL 8
#define N_LINES 50000

typedef float v4f __attribute__((ext_vector_type(4)));  // native vec for nontemporal builtins

// ---------------------------------------------------------------------------
// Pre-pass: transpose features (C,H,W) fp32 -> (H*W, C) fp16.
// fp16 halves the gather working set to 4 MB = one XCD's L2 capacity.
// Tile: 64 pixels x 128 channels via LDS (pad 129 to kill bank conflicts).
// ---------------------------------------------------------------------------
__global__ __launch_bounds__(256) void transpose_chw_hwc(
    const float* __restrict__ in, __half* __restrict__ out) {
    __shared__ float tile[64 * 129];
    const int p0 = blockIdx.x * 64;
    const int t = threadIdx.x;

    const int p_local = t & 63;
    const int cg = t >> 6;  // 0..3, each covers 32 channels
    #pragma unroll
    for (int i = 0; i < 32; ++i) {
        const int ch = cg * 32 + i;
        tile[p_local * 129 + ch] = in[ch * NPIX + p0 + p_local];
    }
    __syncthreads();

    const int ch = t & 127;
    const int pg = t >> 7;  // 0..1, each covers 32 pixels
    #pragma unroll
    for (int i = 0; i < 32; ++i) {
        const int p = pg * 32 + i;
        out[(p0 + p) * C_DEPTH + ch] = __float2half(tile[p * 129 + ch]);
    }
}

// ---------------------------------------------------------------------------
// Main kernel: 1 block = 1 line. 128 threads = 8 pool-groups x 16 ch-groups.
//   f  = t >> 4 : pool group, consumes samples 4f..4f+3 (exact pool window)
//   tg = t & 15 : channel group, owns channels 8*tg .. 8*tg+7
// Per sample-corner a 16-lane group loads 16 lanes x 16 B (8 fp16) = 256 B
// contiguous. Bilinear combine in fp32, running max over the 4 samples.
// Output goes through an LDS tile (stride 9 to dodge bank conflicts) so the
// final global stores are 2x float4 per thread, non-temporal (don't pollute
// L2 -- it needs to hold the 4 MB feature map).
// ---------------------------------------------------------------------------
__global__ __launch_bounds__(128) void line_pool(
    const __half* __restrict__ ft,      // (H*W, C) fp16 transposed features
    const float* __restrict__ lines,    // (N_LINES, 4)
    float* __restrict__ out) {
    __shared__ int4   s_off[N_SAMP];    // corner offsets in elements (x C)
    __shared__ float4 s_w[N_SAMP];      // bilinear weights (w00,w10,w01,w11)
    __shared__ float  o_tile[C_DEPTH * 9];

    const int line = blockIdx.x;
    const int t = threadIdx.x;

    if (t < N_SAMP) {
        const float4 l = reinterpret_cast<const float4*>(lines)[line];
        const float ts = (float)t / 31.0f;  // exact 1.0 at t=31
        const float px = l.x * ts + l.z * (1.0f - ts) - 0.5f;
        const float py = l.y * ts + l.w * (1.0f - ts) - 0.5f;
        // Reference: clamp AFTER floor, weights from the CLAMPED float coords.
        const float px0 = fminf(fmaxf(floorf(px), 0.0f), (float)(W_DIM - 1));
        const float py0 = fminf(fmaxf(floorf(py), 0.0f), (float)(H_DIM - 1));
        const float px1 = fminf(px0 + 1.0f, (float)(W_DIM - 1));
        const float py1 = fminf(py0 + 1.0f, (float)(H_DIM - 1));
        const int ix0 = (int)px0, iy0 = (int)py0;
        const int ix1 = (int)px1, iy1 = (int)py1;
        const float wx0 = px1 - px, wx1 = px - px0;
        const float wy0 = py1 - py, wy1 = py - py0;
        s_off[t] = make_int4((iy0 * W_DIM + ix0) * C_DEPTH,
                             (iy1 * W_DIM + ix0) * C_DEPTH,
                             (iy0 * W_DIM + ix1) * C_DEPTH,
                             (iy1 * W_DIM + ix1) * C_DEPTH);
        s_w[t] = make_float4(wy0 * wx0, wy1 * wx0, wy0 * wx1, wy1 * wx1);
    }
    __syncthreads();

    const int f  = t >> 4;
    const int tg = t & 15;
    const int c0 = tg * 8;

    float acc[8];
    #pragma unroll
    for (int j = 0; j < 8; ++j) acc[j] = -FLT_MAX;

    #pragma unroll
    for (int si = 0; si < 4; ++si) {
        const int s = f * 4 + si;
        const int4   o  = s_off[s];
        const float4 wv = s_w[s];
        const float4 r00 = *reinterpret_cast<const float4*>(ft + o.x + c0);
        const float4 r10 = *reinterpret_cast<const float4*>(ft + o.y + c0);
        const float4 r01 = *reinterpret_cast<const float4*>(ft + o.z + c0);
        const float4 r11 = *reinterpret_cast<const float4*>(ft + o.w + c0);
        const __half2* h00 = reinterpret_cast<const __half2*>(&r00);
        const __half2* h10 = reinterpret_cast<const __half2*>(&r10);
        const __half2* h01 = reinterpret_cast<const __half2*>(&r01);
        const __half2* h11 = reinterpret_cast<const __half2*>(&r11);
        #pragma unroll
        for (int k = 0; k < 4; ++k) {
            const float2 f00 = __half22float2(h00[k]);
            const float2 f10 = __half22float2(h10[k]);
            const float2 f01 = __half22float2(h01[k]);
            const float2 f11 = __half22float2(h11[k]);
            const float vx = f00.x * wv.x + f10.x * wv.y + f01.x * wv.z + f11.x * wv.w;
            const float vy = f00.y * wv.x + f10.y * wv.y + f01.y * wv.z + f11.y * wv.w;
            acc[2 * k]     = fmaxf(acc[2 * k],     vx);
            acc[2 * k + 1] = fmaxf(acc[2 * k + 1], vy);
        }
    }

    // Transpose (f, c) -> (c, f) through LDS; stride 9 => read-back is
    // conflict-free (9 coprime 32), write side only 4-way on 1/8 of traffic.
    #pragma unroll
    for (int j = 0; j < 8; ++j) o_tile[(c0 + j) * 9 + f] = acc[j];
    __syncthreads();

    float* op = out + (size_t)line * (C_DEPTH * N_FINAL) + t * N_FINAL;
    const float* row = &o_tile[t * 9];
    const v4f w0 = {row[0], row[1], row[2], row[3]};
    const v4f w1 = {row[4], row[5], row[6], row[7]};
    __builtin_nontemporal_store(w0, reinterpret_cast<v4f*>(op));
    __builtin_nontemporal_store(w1, reinterpret_cast<v4f*>(op) + 1);
}

extern "C" void kernel_launch(void* const* d_in, const int* in_sizes, int n_in,
                              void* d_out, int out_size, void* d_ws, size_t ws_size,
                              hipStream_t stream) {
    const float* feat  = (const float*)d_in[0];   // (128,128,128) fp32
    const float* lines = (const float*)d_in[1];   // (50000,4) fp32
    float* out = (float*)d_out;                   // (50000, 1024) fp32
    __half* ft = (__half*)d_ws;                   // 4 MB transposed fp16 features

    transpose_chw_hwc<<<NPIX / 64, 256, 0, stream>>>(feat, ft);
    line_pool<<<N_LINES, 128, 0, stream>>>(ft, lines, out);
}